// Round 2
// baseline (3798.799 us; speedup 1.0000x reference)
//
#include <hip/hip_runtime.h>
#include <math.h>

#define NM 40962
#define NG 200000
#define NE 600000

typedef unsigned short u16;
typedef unsigned int u32;

// ---- bf16 helpers (bf16 pair packed in a u32: lo = element 2k, hi = 2k+1) ----
__device__ __forceinline__ float blo(u32 w) { return __uint_as_float(w << 16); }
__device__ __forceinline__ float bhi(u32 w) { return __uint_as_float(w & 0xFFFF0000u); }
__device__ __forceinline__ u32 f2bf(float f) {
  u32 u = __float_as_uint(f);
  u32 r = u + 0x7FFFu + ((u >> 16) & 1u);   // RNE
  return r >> 16;
}
__device__ __forceinline__ u32 pack2(float a, float b) { return f2bf(a) | (f2bf(b) << 16); }
__device__ __forceinline__ float rdlane(float v, int t) {
  return __int_as_float(__builtin_amdgcn_readlane(__float_as_int(v), t));
}
__device__ __forceinline__ float silu(float x) { return x / (1.f + __expf(-x)); }

// Convert fp32 weight matrix (rows x 128) to bf16-pair LDS layout:
// sW[k*64 + l] = { W[k][2l], W[k][2l+1] }   (that is just pairwise packing in order)
__device__ __forceinline__ void stage_weights(const float* __restrict__ W, u32* sW,
                                              int n_u32) {
  const float2* wf = (const float2*)W;
  for (int i = threadIdx.x; i < n_u32; i += 256) {
    float2 w = wf[i];
    sW[i] = pack2(w.x, w.y);
  }
}

// Row-dot: lane holds x[2*lane] (xa), x[2*lane+1] (xb); accumulates output
// columns 2*lane, 2*lane+1 into acc0/acc1.  K = 128.
__device__ __forceinline__ void dot128(const u32* sW, float xa, float xb,
                                       float& acc0, float& acc1, int lane) {
  #pragma unroll 8
  for (int t = 0; t < 64; ++t) {
    float xk0 = rdlane(xa, t);     // x[2t]
    float xk1 = rdlane(xb, t);     // x[2t+1]
    u32 w0 = sW[(2 * t) * 64 + lane];
    u32 w1 = sW[(2 * t + 1) * 64 + lane];
    acc0 += xk0 * blo(w0) + xk1 * blo(w1);
    acc1 += xk0 * bhi(w0) + xk1 * bhi(w1);
  }
}

// ---------------- projection: O[r,:] = bf16(X[r,:] @ W)  (K=128, N=128) ----------------
__global__ __launch_bounds__(256) void proj_kernel(const float* __restrict__ X,
                                                   const float* __restrict__ W,
                                                   u32* __restrict__ O, int nrows) {
  __shared__ u32 sW[128 * 64];
  stage_weights(W, sW, 128 * 64);
  __syncthreads();
  const int lane = threadIdx.x & 63, wave = threadIdx.x >> 6;
  int r0 = blockIdx.x * 128 + wave * 32;
  for (int i = 0; i < 32; ++i) {
    int r = r0 + i;
    if (r >= nrows) break;
    float2 x = ((const float2*)(X + (size_t)r * 128))[lane];
    float a0 = 0.f, a1 = 0.f;
    dot128(sW, x.x, x.y, a0, a1, lane);
    O[(size_t)r * 64 + lane] = pack2(a0, a1);
  }
}

// ---------------- edge TMLP + LN + scatter-add ----------------
__global__ __launch_bounds__(256) void edge_kernel(
    const float* __restrict__ m2g, const u32* __restrict__ PS, const u32* __restrict__ PD,
    const int* __restrict__ src_idx, const int* __restrict__ dst_idx,
    const float* __restrict__ We, const float* __restrict__ b0,
    const float* __restrict__ W1e, const float* __restrict__ b1e,
    const float* __restrict__ ge, const float* __restrict__ be,
    float* __restrict__ agg) {
  __shared__ u32 sWe[128 * 64];
  __shared__ u32 sW1[128 * 64];
  stage_weights(We, sWe, 128 * 64);
  stage_weights(W1e, sW1, 128 * 64);
  __syncthreads();
  const int lane = threadIdx.x & 63, wave = threadIdx.x >> 6;
  float2 b0p = ((const float2*)b0)[lane];
  float2 b1p = ((const float2*)b1e)[lane];
  float2 gep = ((const float2*)ge)[lane];
  float2 bep = ((const float2*)be)[lane];
  int e0 = blockIdx.x * 128 + wave * 32;
  for (int i = 0; i < 32; ++i) {
    int e = e0 + i;
    if (e >= NE) break;
    int s = src_idx[e], dn = dst_idx[e];
    float2 x = ((const float2*)(m2g + (size_t)e * 128))[lane];
    u32 ps = PS[(size_t)s * 64 + lane];
    u32 pd = PD[(size_t)dn * 64 + lane];
    float a0 = b0p.x + blo(ps) + blo(pd);
    float a1 = b0p.y + bhi(ps) + bhi(pd);
    dot128(sWe, x.x, x.y, a0, a1, lane);
    float h0 = silu(a0);
    float h1 = silu(a1);
    float y0 = b1p.x, y1 = b1p.y;
    dot128(sW1, h0, h1, y0, y1, lane);
    // LayerNorm across the 128 outputs (2 per lane)
    float sm = y0 + y1, sq = y0 * y0 + y1 * y1;
    #pragma unroll
    for (int m = 1; m < 64; m <<= 1) {
      sm += __shfl_xor(sm, m, 64);
      sq += __shfl_xor(sq, m, 64);
    }
    float mu = sm * (1.f / 128.f);
    float var = sq * (1.f / 128.f) - mu * mu;
    float rs = rsqrtf(var + 1e-5f);
    float o0 = (y0 - mu) * rs * gep.x + bep.x;
    float o1 = (y1 - mu) * rs * gep.y + bep.y;
    float* ap = agg + (size_t)dn * 128 + 2 * lane;
    atomicAdd(ap, o0);
    atomicAdd(ap + 1, o1);
  }
}

// ---------------- node MLP pass A: hn = silu([grid, agg] @ Wn0 + bn0) ----------------
__global__ __launch_bounds__(256) void node_a_kernel(
    const float* __restrict__ grid, const float* __restrict__ agg,
    const float* __restrict__ Wn0, const float* __restrict__ bn0,
    u32* __restrict__ hn) {
  __shared__ u32 sW0[256 * 64];  // 64 KB
  stage_weights(Wn0, sW0, 256 * 64);
  __syncthreads();
  const int lane = threadIdx.x & 63, wave = threadIdx.x >> 6;
  float2 bp = ((const float2*)bn0)[lane];
  int n0 = blockIdx.x * 128 + wave * 32;
  for (int i = 0; i < 32; ++i) {
    int n = n0 + i;
    if (n >= NG) break;
    float2 x = ((const float2*)(grid + (size_t)n * 128))[lane];
    float2 av = ((const float2*)(agg + (size_t)n * 128))[lane];
    float a0 = bp.x, a1 = bp.y;
    dot128(sW0, x.x, x.y, a0, a1, lane);
    dot128(sW0 + 128 * 64, av.x, av.y, a0, a1, lane);
    hn[(size_t)n * 64 + lane] = pack2(silu(a0), silu(a1));
  }
}

// ---------------- node MLP pass B: out = LN(hn @ Wn1 + bn1)*gn + bn + grid ----------------
__global__ __launch_bounds__(256) void node_b_kernel(
    const u32* __restrict__ hn, const float* __restrict__ grid,
    const float* __restrict__ Wn1, const float* __restrict__ bn1,
    const float* __restrict__ gn, const float* __restrict__ bnv,
    float* __restrict__ out) {
  __shared__ u32 sW1[128 * 64];
  stage_weights(Wn1, sW1, 128 * 64);
  __syncthreads();
  const int lane = threadIdx.x & 63, wave = threadIdx.x >> 6;
  float2 b1 = ((const float2*)bn1)[lane];
  float2 g = ((const float2*)gn)[lane];
  float2 bb = ((const float2*)bnv)[lane];
  int n0 = blockIdx.x * 128 + wave * 32;
  for (int i = 0; i < 32; ++i) {
    int n = n0 + i;
    if (n >= NG) break;
    u32 h = hn[(size_t)n * 64 + lane];
    float y0 = b1.x, y1 = b1.y;
    dot128(sW1, blo(h), bhi(h), y0, y1, lane);
    float sm = y0 + y1, sq = y0 * y0 + y1 * y1;
    #pragma unroll
    for (int m = 1; m < 64; m <<= 1) {
      sm += __shfl_xor(sm, m, 64);
      sq += __shfl_xor(sq, m, 64);
    }
    float mu = sm * (1.f / 128.f);
    float var = sq * (1.f / 128.f) - mu * mu;
    float rs = rsqrtf(var + 1e-5f);
    float2 x = ((const float2*)(grid + (size_t)n * 128))[lane];
    float2 o;
    o.x = (y0 - mu) * rs * g.x + bb.x + x.x;
    o.y = (y1 - mu) * rs * g.y + bb.y + x.y;
    ((float2*)(out + (size_t)n * 128))[lane] = o;
  }
}

extern "C" void kernel_launch(void* const* d_in, const int* in_sizes, int n_in,
                              void* d_out, int out_size, void* d_ws, size_t ws_size,
                              hipStream_t stream) {
  const float* m2g = (const float*)d_in[0];
  const float* grid = (const float*)d_in[1];
  const float* mesh = (const float*)d_in[2];
  const int* src = (const int*)d_in[3];
  const int* dst = (const int*)d_in[4];
  const float* We = (const float*)d_in[5];
  const float* Ws = (const float*)d_in[6];
  const float* Wd = (const float*)d_in[7];
  const float* b0 = (const float*)d_in[8];
  const float* W1e = (const float*)d_in[9];
  const float* b1e = (const float*)d_in[10];
  const float* ge = (const float*)d_in[11];
  const float* be = (const float*)d_in[12];
  const float* Wn0 = (const float*)d_in[13];
  const float* bn0 = (const float*)d_in[14];
  const float* Wn1 = (const float*)d_in[15];
  const float* bn1 = (const float*)d_in[16];
  const float* gn = (const float*)d_in[17];
  const float* bnv = (const float*)d_in[18];
  (void)in_sizes; (void)n_in; (void)out_size; (void)ws_size;

  char* ws = (char*)d_ws;
  float* agg = (float*)ws;                       // 200000*128 f32 = 102,400,000 B
  size_t aggB = (size_t)NG * 128 * 4;
  u32* PS = (u32*)(ws + aggB);                   // 40962*64 u32 = 10,486,272 B
  size_t psB = (size_t)NM * 64 * 4;
  u32* PD = (u32*)(ws + aggB + psB);             // 200000*64 u32 = 51,200,000 B
  u32* HN = PD;                                  // reuse PD region for hn (PD dead after edge_kernel)

  hipMemsetAsync(agg, 0, aggB, stream);
  proj_kernel<<<(NM + 127) / 128, 256, 0, stream>>>(mesh, Ws, PS, NM);
  proj_kernel<<<(NG + 127) / 128, 256, 0, stream>>>(grid, Wd, PD, NG);
  edge_kernel<<<(NE + 127) / 128, 256, 0, stream>>>(m2g, PS, PD, src, dst, We, b0, W1e,
                                                    b1e, ge, be, agg);
  node_a_kernel<<<(NG + 127) / 128, 256, 0, stream>>>(grid, agg, Wn0, bn0, HN);
  node_b_kernel<<<(NG + 127) / 128, 256, 0, stream>>>(HN, grid, Wn1, bn1, gn, bnv,
                                                      (float*)d_out);
}